// Round 10
// baseline (138.061 us; speedup 1.0000x reference)
//
#include <hip/hip_runtime.h>
#include <math.h>

// AWLoss closed-form: f = 24 - (0.5/511^2) * sum_c S1_c^2 / S2_c
// S1 = sum wgt*Re(F), S2 = sum wgt*|F|^2 over half-spectrum k1 in [0,511),
// k2 in [0,256), wgt = 1 for k2==0 else 2, F = conj(X)Y / |X|^2
// (1e-9 pre-whitening is < 1e-12 relative to |X|^2 ~ 1e4 -> dropped).
// X = DFT2(pad(target)), Y = DFT2(pad(recon)), pad offset 127.
//
// Round-10 stage2: twiddle-stationary / x1t-streamed (inverts R6-R9, which all
// hit 42-53us by pinning x1t frags into registers). Block = (t, kt-octave,
// 6-ch group); wave holds 2 kt's twiddle frags in VGPRs (loop-invariant, no asm
// pins), x1t slices staged per-channel into LDS via global_load_lds with a
// double buffer (one barrier per channel). 512 blocks, 2 blocks/CU.

#define NCH 48
#define PADOFF 127
#define TWO_PI_F 6.283185307179586f

typedef float f32x4 __attribute__((ext_vector_type(4)));
typedef short s16x8 __attribute__((ext_vector_type(8)));
typedef unsigned short u16;

typedef __attribute__((address_space(1))) const unsigned char* gas_p;
typedef __attribute__((address_space(3))) unsigned char* las_p;

union frag_u { u16 u[8]; s16x8 v; };

__device__ __forceinline__ u16 f2bf(float f) {
    union { float f; unsigned u; } x; x.f = f;
    unsigned r = x.u + 0x7FFFu + ((x.u >> 16) & 1u);
    return (u16)(r >> 16);
}

#define MFMA16(A, B, C) __builtin_amdgcn_mfma_f32_16x16x32_bf16(A, B, C, 0, 0, 0)

// ---------------- setup: twiddle fragment table + acc zero ----------------
// w2f : fragments [kt(32)][c(2)][kk(8)][lane(64)][j(8)] bf16
//       element: tw((16kt + (l&15)) * (32kk + 8(l>>4) + j + 127) mod 511),
//       c=0 cos, c=1 sin; rows k1>=511 zeroed.
__global__ __launch_bounds__(256) void setup(u16* __restrict__ w2f,
                                             float* __restrict__ sacc) {
    __shared__ float cs[511], sn[511];
    int tid = threadIdx.x;
    for (int i = tid; i < 511; i += 256) {
        float a = -TWO_PI_F * (float)i / 511.0f;
        cs[i] = cosf(a);
        sn[i] = sinf(a);
    }
    __syncthreads();

    int i = blockIdx.x * 256 + tid;      // i < 262144
    int j = i & 7, l = (i >> 3) & 63, kk = (i >> 9) & 7;
    int c = (i >> 12) & 1, kt = i >> 13;
    int k1 = 16 * kt + (l & 15);
    u16 v = 0;
    if (k1 < 511) {
        int n = 32 * kk + 8 * (l >> 4) + j;
        int p = (k1 * (n + PADOFF)) % 511;
        v = f2bf(c ? sn[p] : cs[p]);
    }
    w2f[i] = v;
    if (blockIdx.x == 0 && tid < 2 * NCH) sacc[tid] = 0.0f;
}

// ---------------- LDS fill helper: 128 KiB, 512 threads ----------------
__device__ __forceinline__ void fill_tw(u16* tw, const u16* gp, int tid) {
    s16x8 tmp[16];
    #pragma unroll
    for (int i = 0; i < 16; ++i)
        tmp[i] = *(const s16x8*)(gp + (size_t)(tid + 512 * i) * 8);
    #pragma unroll
    for (int i = 0; i < 16; ++i)
        *(s16x8*)&tw[(size_t)(tid + 512 * i) * 8] = tmp[i];
}

// ---------------- stage 1: DFT along W (MFMA, LDS-resident twiddles) ----------------
// X1[n1][k2] = sum_b src[n1][b] * W[b][k2]; x1t[lc*4+tsel*2+c][k2][n1] bf16.
// grid = 256 blocks x 512 thr: th = bid&1 (t-half in LDS), task = (img, mp).
__global__ __launch_bounds__(512, 2) void stage1(const float* __restrict__ target,
                                                 const float* __restrict__ recon,
                                                 const u16* __restrict__ w2f,
                                                 u16* __restrict__ x1t,
                                                 int c0, int cc) {
    int tid = threadIdx.x;
    int w = tid >> 6, l = tid & 63;
    int lm = l & 15, lh = l >> 4;
    int th = blockIdx.x & 1;
    int bidh = blockIdx.x >> 1;          // 0..127

    __shared__ u16 tw[65536];            // 128 KiB: 8 t-tiles [tt][c][kk][l][8]
    fill_tw(tw, w2f + (size_t)th * 65536, tid);
    __syncthreads();

    int ntasks = 16 * cc;                // (img = 2cc) x (mp = 8)
    int task = bidh * 8 + w;
    if (task >= ntasks) return;
    int img = task >> 3;
    int mp  = task & 7;
    int lc = img >> 1;
    int tsel = img & 1;
    const float* src = (tsel == 0 ? target : recon) + (size_t)(c0 + lc) * 65536;

    frag_u af[2][8];
    #pragma unroll
    for (int a = 0; a < 2; ++a) {
        const float* ap = src + (size_t)(32 * mp + 16 * a + lm) * 256 + 8 * lh;
        #pragma unroll
        for (int kk = 0; kk < 8; ++kk) {
            float4 v0 = *(const float4*)(ap + 32 * kk);
            float4 v1 = *(const float4*)(ap + 32 * kk + 4);
            af[a][kk].u[0] = f2bf(v0.x); af[a][kk].u[1] = f2bf(v0.y);
            af[a][kk].u[2] = f2bf(v0.z); af[a][kk].u[3] = f2bf(v0.w);
            af[a][kk].u[4] = f2bf(v1.x); af[a][kk].u[5] = f2bf(v1.y);
            af[a][kk].u[6] = f2bf(v1.z); af[a][kk].u[7] = f2bf(v1.w);
        }
    }

    u16* chdst = x1t + (size_t)(lc * 4 + tsel * 2) * 65536;

    for (int tt = 0; tt < 8; ++tt) {
        int t = 8 * th + tt;
        f32x4 ac0 = {0,0,0,0}, as0 = {0,0,0,0}, ac1 = {0,0,0,0}, as1 = {0,0,0,0};
        #pragma unroll
        for (int kk = 0; kk < 8; ++kk) {
            s16x8 bc = *(const s16x8*)&tw[tt * 8192 + kk * 512 + l * 8];
            s16x8 bs = *(const s16x8*)&tw[tt * 8192 + 4096 + kk * 512 + l * 8];
            ac0 = MFMA16(af[0][kk].v, bc, ac0);
            as0 = MFMA16(af[0][kk].v, bs, as0);
            ac1 = MFMA16(af[1][kk].v, bc, ac1);
            as1 = MFMA16(af[1][kk].v, bs, as1);
        }
        ushort4 o0, o1;
        o0.x = f2bf(ac0[0]); o0.y = f2bf(ac0[1]);
        o0.z = f2bf(ac0[2]); o0.w = f2bf(ac0[3]);
        o1.x = f2bf(as0[0]); o1.y = f2bf(as0[1]);
        o1.z = f2bf(as0[2]); o1.w = f2bf(as0[3]);
        size_t off = (size_t)(16 * t + lm) * 256 + 32 * mp + 4 * lh;
        *(ushort4*)(chdst + off)         = o0;
        *(ushort4*)(chdst + 65536 + off) = o1;
        o0.x = f2bf(ac1[0]); o0.y = f2bf(ac1[1]);
        o0.z = f2bf(ac1[2]); o0.w = f2bf(ac1[3]);
        o1.x = f2bf(as1[0]); o1.y = f2bf(as1[1]);
        o1.z = f2bf(as1[2]); o1.w = f2bf(as1[3]);
        *(ushort4*)(chdst + off + 16)         = o0;
        *(ushort4*)(chdst + 65536 + off + 16) = o1;
    }
}

// ---------------- stage 2: twiddle-stationary, x1t streamed via LDS ----------------
// grid = 64*ngrp blocks x 256 thr: t = bid&15, o = (bid>>4)&3, chg = bid>>6.
// Wave w: kt pair {8o+2w, 8o+2w+1} twiddles stationary in VGPRs. Per channel:
// 32KB x1t slice async-staged to LDS (double-buffered, 1 barrier/ch).
__global__ __launch_bounds__(256, 2) void stage2(const u16* __restrict__ x1t,
                                                 const u16* __restrict__ w2f,
                                                 float* __restrict__ sacc,
                                                 int c0, int cc) {
    int tid = threadIdx.x;
    int w = tid >> 6, l = tid & 63;
    int lm = l & 15, lh = l >> 4;
    int t   = blockIdx.x & 15;
    int o   = (blockIdx.x >> 4) & 3;
    int chg = blockIdx.x >> 6;
    int ch0 = chg * 6;
    int nch = cc - ch0; if (nch > 6) nch = 6;
    if (nch <= 0) return;

    __shared__ u16 sbuf[2][16384];       // 2 x 32 KiB: [(p*8+kk)*512 + l*8]

    // stationary twiddle frags for kt0 = 8o+2w and kt0+1
    int kt0 = 8 * o + 2 * w;
    s16x8 twr0[8], twi0[8], twr1[8], twi1[8];
    {
        const u16* p0 = w2f + (size_t)kt0 * 8192 + l * 8;
        const u16* p1 = w2f + (size_t)(kt0 + 1) * 8192 + l * 8;
        #pragma unroll
        for (int kk = 0; kk < 8; ++kk) {
            twr0[kk] = *(const s16x8*)(p0 + kk * 512);
            twi0[kk] = *(const s16x8*)(p0 + 4096 + kk * 512);
            twr1[kk] = *(const s16x8*)(p1 + kk * 512);
            twi1[kk] = *(const s16x8*)(p1 + 4096 + kk * 512);
        }
    }

    int k2 = 16 * t + lm;
    float wgt = (k2 == 0) ? 1.f : 2.f;
    int rowoff = (16 * t + lm) * 256 + 8 * lh;   // per-lane x1t row/col offset

#define STAGE(BUF, LC) do {                                                   \
    const u16* cb_ = x1t + (size_t)(4 * (LC)) * 65536;                        \
    _Pragma("unroll")                                                         \
    for (int q = 0; q < 8; ++q) {                                             \
        int pair_ = w * 8 + q;                                                \
        int p_ = pair_ >> 3, kk_ = pair_ & 7;                                 \
        const u16* g_ = cb_ + (size_t)p_ * 65536 + rowoff + 32 * kk_;         \
        __builtin_amdgcn_global_load_lds((gas_p)g_,                           \
            (las_p)&sbuf[BUF][pair_ * 512], 16, 0, 0);                        \
    } } while (0)

    STAGE(0, ch0);
    __syncthreads();

    for (int i = 0; i < nch; ++i) {
        int buf = i & 1;
        if (i + 1 < nch) STAGE(buf ^ 1, ch0 + i + 1);

        f32x4 c0rr = {0,0,0,0}, c0ii = {0,0,0,0}, c0ri = {0,0,0,0}, c0ir = {0,0,0,0};
        f32x4 d0rr = {0,0,0,0}, d0ii = {0,0,0,0}, d0ri = {0,0,0,0}, d0ir = {0,0,0,0};
        f32x4 c1rr = {0,0,0,0}, c1ii = {0,0,0,0}, c1ri = {0,0,0,0}, c1ir = {0,0,0,0};
        f32x4 d1rr = {0,0,0,0}, d1ii = {0,0,0,0}, d1ri = {0,0,0,0}, d1ir = {0,0,0,0};

        #pragma unroll
        for (int kk = 0; kk < 8; ++kk) {
            const u16* fb = &sbuf[buf][kk * 512 + l * 8];
            s16x8 ar = *(const s16x8*)(fb);
            s16x8 ai = *(const s16x8*)(fb + 4096);
            s16x8 br = *(const s16x8*)(fb + 8192);
            s16x8 bi = *(const s16x8*)(fb + 12288);
            c0rr = MFMA16(twr0[kk], ar, c0rr);
            c0ii = MFMA16(twi0[kk], ai, c0ii);
            c0ri = MFMA16(twr0[kk], ai, c0ri);
            c0ir = MFMA16(twi0[kk], ar, c0ir);
            d0rr = MFMA16(twr0[kk], br, d0rr);
            d0ii = MFMA16(twi0[kk], bi, d0ii);
            d0ri = MFMA16(twr0[kk], bi, d0ri);
            d0ir = MFMA16(twi0[kk], br, d0ir);
            c1rr = MFMA16(twr1[kk], ar, c1rr);
            c1ii = MFMA16(twi1[kk], ai, c1ii);
            c1ri = MFMA16(twr1[kk], ai, c1ri);
            c1ir = MFMA16(twi1[kk], ar, c1ir);
            d1rr = MFMA16(twr1[kk], br, d1rr);
            d1ii = MFMA16(twi1[kk], bi, d1ii);
            d1ri = MFMA16(twr1[kk], bi, d1ri);
            d1ir = MFMA16(twi1[kk], br, d1ir);
        }

        float s1 = 0.f, s2 = 0.f;
        #pragma unroll
        for (int r = 0; r < 4; ++r) {
            {   // kt0 (k1 <= 495 always valid)
                float Xr = c0rr[r] - c0ii[r], Xi = c0ri[r] + c0ir[r];
                float Yr = d0rr[r] - d0ii[r], Yi = d0ri[r] + d0ir[r];
                float Pr = Xr * Yr + Xi * Yi;
                float Pi = Xr * Yi - Xi * Yr;
                float Q  = Xr * Xr + Xi * Xi;
                float inv = 1.0f / (Q * Q + 1e-30f);
                s1 += wgt * Pr * Q * inv;
                s2 += wgt * (Pr * Pr + Pi * Pi) * inv;
            }
            {   // kt1
                int k1 = 16 * (kt0 + 1) + 4 * lh + r;
                float wg2 = (k1 < 511) ? wgt : 0.f;
                float Xr = c1rr[r] - c1ii[r], Xi = c1ri[r] + c1ir[r];
                float Yr = d1rr[r] - d1ii[r], Yi = d1ri[r] + d1ir[r];
                float Pr = Xr * Yr + Xi * Yi;
                float Pi = Xr * Yi - Xi * Yr;
                float Q  = Xr * Xr + Xi * Xi;
                float inv = 1.0f / (Q * Q + 1e-30f);
                s1 += wg2 * Pr * Q * inv;
                s2 += wg2 * (Pr * Pr + Pi * Pi) * inv;
            }
        }

        #pragma unroll
        for (int off = 32; off > 0; off >>= 1) {
            s1 += __shfl_down(s1, off);
            s2 += __shfl_down(s2, off);
        }
        if (l == 0) {
            atomicAdd(&sacc[c0 + ch0 + i], s1);
            atomicAdd(&sacc[NCH + c0 + ch0 + i], s2);
        }
        __syncthreads();                 // staging done + all waves done with buf
    }
#undef STAGE
}

__global__ void finalize(const float* __restrict__ s, float* __restrict__ out) {
    int t = threadIdx.x;
    float v = 0.f;
    if (t < NCH) {
        float s1 = s[t], s2 = s[NCH + t];
        v = (s2 != 0.f) ? (s1 * s1) / s2 : 0.f;
    }
    for (int off = 32; off > 0; off >>= 1) v += __shfl_down(v, off);
    if (t == 0) out[0] = 24.0f - 0.5f * v / 261121.0f;
}

// ---------------- launch ----------------
extern "C" void kernel_launch(void* const* d_in, const int* in_sizes, int n_in,
                              void* d_out, int out_size, void* d_ws, size_t ws_size,
                              hipStream_t stream) {
    const float* recon  = (const float*)d_in[0];
    const float* target = (const float*)d_in[1];
    float* out = (float*)d_out;
    char* ws = (char*)d_ws;

    const size_t OFF_W2F = 0;                        // 524288 B
    const size_t OFF_S   = OFF_W2F + 524288;         // 512 B
    const size_t OFF_X1  = OFF_S + 512;

    u16*   w2f  = (u16*)(ws + OFF_W2F);
    float* sacc = (float*)(ws + OFF_S);
    u16*   x1t  = (u16*)(ws + OFF_X1);

    const size_t perch = 4ull * 65536 * 2;           // 512 KiB per channel
    size_t avail = (ws_size > OFF_X1) ? ws_size - OFF_X1 : 0;
    int chunk = (int)(avail / perch);
    if (chunk > NCH) chunk = NCH;
    if (chunk < 1) chunk = 1;

    setup<<<dim3(1024), dim3(256), 0, stream>>>(w2f, sacc);

    for (int c0 = 0; c0 < NCH; c0 += chunk) {
        int cc = (NCH - c0 < chunk) ? (NCH - c0) : chunk;
        int ngrp = (cc + 5) / 6;
        stage1<<<dim3(256), dim3(512), 0, stream>>>(target, recon, w2f, x1t, c0, cc);
        stage2<<<dim3(64 * ngrp), dim3(256), 0, stream>>>(x1t, w2f, sacc, c0, cc);
    }
    finalize<<<dim3(1), dim3(64), 0, stream>>>(sacc, out);
}

// Round 11
// 66.997 us; speedup vs baseline: 2.0607x; 2.0607x over previous
//
#include <hip/hip_runtime.h>
#include <math.h>

// AWLoss closed-form: f = 24 - (0.5/511^2) * sum_c S1_c^2 / S2_c
// S1 = sum wgt*Re(F), S2 = sum wgt*|F|^2 over half-spectrum k1 in [0,511),
// k2 in [0,256), wgt = 1 for k2==0 else 2, F = conj(X)Y / |X|^2
// (1e-9 pre-whitening is < 1e-12 relative to |X|^2 ~ 1e4 -> dropped).
// X = DFT2(pad(target)), Y = DFT2(pad(recon)), pad offset 127.
//
// Round-11: R10's twiddle-stationary stage2 with the serializers removed:
//  - per-channel sums kept in registers (static unroll), atomics ONCE per
//    block after the last barrier (R10's step-coupled contended atomics were
//    the 109us: replays showed same dur with zero HBM traffic);
//  - two named LDS buffers + 2-channel unrolled loop (no runtime buf index,
//    no ds_read/global_load_lds alias stalls);
//  - stage1: quarter-LDS (64KB) twiddle residency, 2 blocks/CU, grid 512.

#define NCH 48
#define PADOFF 127
#define TWO_PI_F 6.283185307179586f

typedef float f32x4 __attribute__((ext_vector_type(4)));
typedef short s16x8 __attribute__((ext_vector_type(8)));
typedef unsigned short u16;

typedef __attribute__((address_space(1))) const unsigned char* gas_p;
typedef __attribute__((address_space(3))) unsigned char* las_p;

union frag_u { u16 u[8]; s16x8 v; };

__device__ __forceinline__ u16 f2bf(float f) {
    union { float f; unsigned u; } x; x.f = f;
    unsigned r = x.u + 0x7FFFu + ((x.u >> 16) & 1u);
    return (u16)(r >> 16);
}

#define MFMA16(A, B, C) __builtin_amdgcn_mfma_f32_16x16x32_bf16(A, B, C, 0, 0, 0)

// ---------------- setup: twiddle fragment table + acc zero ----------------
// w2f : fragments [kt(32)][c(2)][kk(8)][lane(64)][j(8)] bf16
//       element: tw((16kt + (l&15)) * (32kk + 8(l>>4) + j + 127) mod 511),
//       c=0 cos, c=1 sin; rows k1>=511 zeroed.
__global__ __launch_bounds__(256) void setup(u16* __restrict__ w2f,
                                             float* __restrict__ sacc) {
    __shared__ float cs[511], sn[511];
    int tid = threadIdx.x;
    for (int i = tid; i < 511; i += 256) {
        float a = -TWO_PI_F * (float)i / 511.0f;
        cs[i] = cosf(a);
        sn[i] = sinf(a);
    }
    __syncthreads();

    int i = blockIdx.x * 256 + tid;      // i < 262144
    int j = i & 7, l = (i >> 3) & 63, kk = (i >> 9) & 7;
    int c = (i >> 12) & 1, kt = i >> 13;
    int k1 = 16 * kt + (l & 15);
    u16 v = 0;
    if (k1 < 511) {
        int n = 32 * kk + 8 * (l >> 4) + j;
        int p = (k1 * (n + PADOFF)) % 511;
        v = f2bf(c ? sn[p] : cs[p]);
    }
    w2f[i] = v;
    if (blockIdx.x == 0 && tid < 2 * NCH) sacc[tid] = 0.0f;
}

// ---------------- stage 1: DFT along W (MFMA, quarter-LDS twiddles) ----------------
// X1[n1][k2] = sum_b src[n1][b] * W[b][k2]; x1t[lc*4+tsel*2+c][k2][n1] bf16.
// grid = 512 x 512thr: tq = bid&3 (4 t-tiles in 64KB LDS), task = (img, mp).
__global__ __launch_bounds__(512, 2) void stage1(const float* __restrict__ target,
                                                 const float* __restrict__ recon,
                                                 const u16* __restrict__ w2f,
                                                 u16* __restrict__ x1t,
                                                 int c0, int cc) {
    int tid = threadIdx.x;
    int w = tid >> 6, l = tid & 63;
    int lm = l & 15, lh = l >> 4;
    int tq = blockIdx.x & 3;
    int bidh = blockIdx.x >> 2;          // 0..127

    __shared__ u16 tw[32768];            // 64 KiB: 4 t-tiles [tt][c][kk][l][8]
    {
        const u16* gp = w2f + (size_t)tq * 32768;
        s16x8 tmp[8];
        #pragma unroll
        for (int i = 0; i < 8; ++i)
            tmp[i] = *(const s16x8*)(gp + (size_t)(tid + 512 * i) * 8);
        #pragma unroll
        for (int i = 0; i < 8; ++i)
            *(s16x8*)&tw[(size_t)(tid + 512 * i) * 8] = tmp[i];
    }
    __syncthreads();

    int ntasks = 16 * cc;                // (img = 2cc) x (mp = 8)
    int task = bidh * 8 + w;
    if (task >= ntasks) return;
    int img = task >> 3;
    int mp  = task & 7;
    int lc = img >> 1;
    int tsel = img & 1;
    const float* src = (tsel == 0 ? target : recon) + (size_t)(c0 + lc) * 65536;

    frag_u af[2][8];
    #pragma unroll
    for (int a = 0; a < 2; ++a) {
        const float* ap = src + (size_t)(32 * mp + 16 * a + lm) * 256 + 8 * lh;
        #pragma unroll
        for (int kk = 0; kk < 8; ++kk) {
            float4 v0 = *(const float4*)(ap + 32 * kk);
            float4 v1 = *(const float4*)(ap + 32 * kk + 4);
            af[a][kk].u[0] = f2bf(v0.x); af[a][kk].u[1] = f2bf(v0.y);
            af[a][kk].u[2] = f2bf(v0.z); af[a][kk].u[3] = f2bf(v0.w);
            af[a][kk].u[4] = f2bf(v1.x); af[a][kk].u[5] = f2bf(v1.y);
            af[a][kk].u[6] = f2bf(v1.z); af[a][kk].u[7] = f2bf(v1.w);
        }
    }

    u16* chdst = x1t + (size_t)(lc * 4 + tsel * 2) * 65536;

    #pragma unroll
    for (int tt = 0; tt < 4; ++tt) {
        int t = 4 * tq + tt;
        f32x4 ac0 = {0,0,0,0}, as0 = {0,0,0,0}, ac1 = {0,0,0,0}, as1 = {0,0,0,0};
        #pragma unroll
        for (int kk = 0; kk < 8; ++kk) {
            s16x8 bc = *(const s16x8*)&tw[tt * 8192 + kk * 512 + l * 8];
            s16x8 bs = *(const s16x8*)&tw[tt * 8192 + 4096 + kk * 512 + l * 8];
            ac0 = MFMA16(af[0][kk].v, bc, ac0);
            as0 = MFMA16(af[0][kk].v, bs, as0);
            ac1 = MFMA16(af[1][kk].v, bc, ac1);
            as1 = MFMA16(af[1][kk].v, bs, as1);
        }
        ushort4 o0, o1;
        o0.x = f2bf(ac0[0]); o0.y = f2bf(ac0[1]);
        o0.z = f2bf(ac0[2]); o0.w = f2bf(ac0[3]);
        o1.x = f2bf(as0[0]); o1.y = f2bf(as0[1]);
        o1.z = f2bf(as0[2]); o1.w = f2bf(as0[3]);
        size_t off = (size_t)(16 * t + lm) * 256 + 32 * mp + 4 * lh;
        *(ushort4*)(chdst + off)         = o0;
        *(ushort4*)(chdst + 65536 + off) = o1;
        o0.x = f2bf(ac1[0]); o0.y = f2bf(ac1[1]);
        o0.z = f2bf(ac1[2]); o0.w = f2bf(ac1[3]);
        o1.x = f2bf(as1[0]); o1.y = f2bf(as1[1]);
        o1.z = f2bf(as1[2]); o1.w = f2bf(as1[3]);
        *(ushort4*)(chdst + off + 16)         = o0;
        *(ushort4*)(chdst + 65536 + off + 16) = o1;
    }
}

// ---------------- stage 2: twiddle-stationary, x1t streamed via LDS ----------------
// grid = 64*ngrp x 256 thr: t = bid&15, o = (bid>>4)&3, chg = bid>>6.
// Wave w: kt pair {8o+2w, 8o+2w+1} twiddles stationary in VGPRs. Channels
// double-buffered through two NAMED LDS buffers; per-channel sums in regs;
// one block-reduce + 12 atomics at kernel end (after last barrier).
__global__ __launch_bounds__(256, 2) void stage2(const u16* __restrict__ x1t,
                                                 const u16* __restrict__ w2f,
                                                 float* __restrict__ sacc,
                                                 int c0, int cc) {
    int tid = threadIdx.x;
    int w = tid >> 6, l = tid & 63;
    int lm = l & 15, lh = l >> 4;
    int t   = blockIdx.x & 15;
    int o   = (blockIdx.x >> 4) & 3;
    int chg = blockIdx.x >> 6;
    int ch0 = chg * 6;
    int nch = cc - ch0; if (nch > 6) nch = 6;
    if (nch <= 0) return;

    __shared__ u16 sbufA[16384];         // 32 KiB each: [(p*8+kk)*512 + l*8]
    __shared__ u16 sbufB[16384];
    __shared__ float red[4][12];

    int kt0 = 8 * o + 2 * w;
    s16x8 twr0[8], twi0[8], twr1[8], twi1[8];
    {
        const u16* p0 = w2f + (size_t)kt0 * 8192 + l * 8;
        const u16* p1 = w2f + (size_t)(kt0 + 1) * 8192 + l * 8;
        #pragma unroll
        for (int kk = 0; kk < 8; ++kk) {
            twr0[kk] = *(const s16x8*)(p0 + kk * 512);
            twi0[kk] = *(const s16x8*)(p0 + 4096 + kk * 512);
            twr1[kk] = *(const s16x8*)(p1 + kk * 512);
            twi1[kk] = *(const s16x8*)(p1 + 4096 + kk * 512);
        }
    }

    int k2 = 16 * t + lm;
    float wgt = (k2 == 0) ? 1.f : 2.f;
    int rowoff = (16 * t + lm) * 256 + 8 * lh;
    float s1a[6] = {0,0,0,0,0,0}, s2a[6] = {0,0,0,0,0,0};

#define STAGE(BUF, LC) do {                                                   \
    const u16* cb_ = x1t + (size_t)(4 * (LC)) * 65536;                        \
    _Pragma("unroll")                                                         \
    for (int q = 0; q < 8; ++q) {                                             \
        int pair_ = w * 8 + q;                                                \
        int p_ = pair_ >> 3, kk_ = pair_ & 7;                                 \
        const u16* g_ = cb_ + (size_t)p_ * 65536 + rowoff + 32 * kk_;         \
        __builtin_amdgcn_global_load_lds((gas_p)g_,                           \
            (las_p)&BUF[pair_ * 512], 16, 0, 0);                              \
    } } while (0)

#define COMPUTE(BUF, I) do {                                                  \
    f32x4 c0rr = {0,0,0,0}, c0ii = {0,0,0,0}, c0ri = {0,0,0,0}, c0ir = {0,0,0,0}; \
    f32x4 d0rr = {0,0,0,0}, d0ii = {0,0,0,0}, d0ri = {0,0,0,0}, d0ir = {0,0,0,0}; \
    f32x4 c1rr = {0,0,0,0}, c1ii = {0,0,0,0}, c1ri = {0,0,0,0}, c1ir = {0,0,0,0}; \
    f32x4 d1rr = {0,0,0,0}, d1ii = {0,0,0,0}, d1ri = {0,0,0,0}, d1ir = {0,0,0,0}; \
    _Pragma("unroll")                                                         \
    for (int kk = 0; kk < 8; ++kk) {                                          \
        const u16* fb = &BUF[kk * 512 + l * 8];                               \
        s16x8 ar = *(const s16x8*)(fb);                                       \
        s16x8 ai = *(const s16x8*)(fb + 4096);                                \
        s16x8 br = *(const s16x8*)(fb + 8192);                                \
        s16x8 bi = *(const s16x8*)(fb + 12288);                               \
        c0rr = MFMA16(twr0[kk], ar, c0rr);                                    \
        c0ii = MFMA16(twi0[kk], ai, c0ii);                                    \
        c0ri = MFMA16(twr0[kk], ai, c0ri);                                    \
        c0ir = MFMA16(twi0[kk], ar, c0ir);                                    \
        d0rr = MFMA16(twr0[kk], br, d0rr);                                    \
        d0ii = MFMA16(twi0[kk], bi, d0ii);                                    \
        d0ri = MFMA16(twr0[kk], bi, d0ri);                                    \
        d0ir = MFMA16(twi0[kk], br, d0ir);                                    \
        c1rr = MFMA16(twr1[kk], ar, c1rr);                                    \
        c1ii = MFMA16(twi1[kk], ai, c1ii);                                    \
        c1ri = MFMA16(twr1[kk], ai, c1ri);                                    \
        c1ir = MFMA16(twi1[kk], ar, c1ir);                                    \
        d1rr = MFMA16(twr1[kk], br, d1rr);                                    \
        d1ii = MFMA16(twi1[kk], bi, d1ii);                                    \
        d1ri = MFMA16(twr1[kk], bi, d1ri);                                    \
        d1ir = MFMA16(twi1[kk], br, d1ir);                                    \
    }                                                                         \
    _Pragma("unroll")                                                         \
    for (int r = 0; r < 4; ++r) {                                             \
        {                                                                     \
            float Xr = c0rr[r] - c0ii[r], Xi = c0ri[r] + c0ir[r];             \
            float Yr = d0rr[r] - d0ii[r], Yi = d0ri[r] + d0ir[r];             \
            float Pr = Xr * Yr + Xi * Yi;                                     \
            float Pi = Xr * Yi - Xi * Yr;                                     \
            float Q  = Xr * Xr + Xi * Xi;                                     \
            float inv = 1.0f / (Q * Q + 1e-30f);                              \
            s1a[I] += wgt * Pr * Q * inv;                                     \
            s2a[I] += wgt * (Pr * Pr + Pi * Pi) * inv;                        \
        }                                                                     \
        {                                                                     \
            int k1 = 16 * (kt0 + 1) + 4 * lh + r;                             \
            float wg2 = (k1 < 511) ? wgt : 0.f;                               \
            float Xr = c1rr[r] - c1ii[r], Xi = c1ri[r] + c1ir[r];             \
            float Yr = d1rr[r] - d1ii[r], Yi = d1ri[r] + d1ir[r];             \
            float Pr = Xr * Yr + Xi * Yi;                                     \
            float Pi = Xr * Yi - Xi * Yr;                                     \
            float Q  = Xr * Xr + Xi * Xi;                                     \
            float inv = 1.0f / (Q * Q + 1e-30f);                              \
            s1a[I] += wg2 * Pr * Q * inv;                                     \
            s2a[I] += wg2 * (Pr * Pr + Pi * Pi) * inv;                        \
        }                                                                     \
    } } while (0)

    STAGE(sbufA, ch0);
    __syncthreads();

    #pragma unroll
    for (int i = 0; i < 6; i += 2) {
        if (i >= nch) break;
        if (i + 1 < nch) STAGE(sbufB, ch0 + i + 1);
        COMPUTE(sbufA, i);
        __syncthreads();
        if (i + 1 < nch) {
            if (i + 2 < nch) STAGE(sbufA, ch0 + i + 2);
            COMPUTE(sbufB, i + 1);
            __syncthreads();
        }
    }
#undef STAGE
#undef COMPUTE

    // wave reduce each channel's pair, then block reduce, then 12 atomics
    #pragma unroll
    for (int i = 0; i < 6; ++i) {
        #pragma unroll
        for (int off = 32; off > 0; off >>= 1) {
            s1a[i] += __shfl_down(s1a[i], off);
            s2a[i] += __shfl_down(s2a[i], off);
        }
    }
    if (l == 0) {
        #pragma unroll
        for (int i = 0; i < 6; ++i) {
            red[w][2 * i]     = s1a[i];
            red[w][2 * i + 1] = s2a[i];
        }
    }
    __syncthreads();
    if (tid < 12) {
        int i = tid >> 1;
        if (i < nch) {
            float v = red[0][tid] + red[1][tid] + red[2][tid] + red[3][tid];
            atomicAdd(&sacc[(tid & 1) * NCH + c0 + ch0 + i], v);
        }
    }
}

__global__ void finalize(const float* __restrict__ s, float* __restrict__ out) {
    int t = threadIdx.x;
    float v = 0.f;
    if (t < NCH) {
        float s1 = s[t], s2 = s[NCH + t];
        v = (s2 != 0.f) ? (s1 * s1) / s2 : 0.f;
    }
    for (int off = 32; off > 0; off >>= 1) v += __shfl_down(v, off);
    if (t == 0) out[0] = 24.0f - 0.5f * v / 261121.0f;
}

// ---------------- launch ----------------
extern "C" void kernel_launch(void* const* d_in, const int* in_sizes, int n_in,
                              void* d_out, int out_size, void* d_ws, size_t ws_size,
                              hipStream_t stream) {
    const float* recon  = (const float*)d_in[0];
    const float* target = (const float*)d_in[1];
    float* out = (float*)d_out;
    char* ws = (char*)d_ws;

    const size_t OFF_W2F = 0;                        // 524288 B
    const size_t OFF_S   = OFF_W2F + 524288;         // 512 B
    const size_t OFF_X1  = OFF_S + 512;

    u16*   w2f  = (u16*)(ws + OFF_W2F);
    float* sacc = (float*)(ws + OFF_S);
    u16*   x1t  = (u16*)(ws + OFF_X1);

    const size_t perch = 4ull * 65536 * 2;           // 512 KiB per channel
    size_t avail = (ws_size > OFF_X1) ? ws_size - OFF_X1 : 0;
    int chunk = (int)(avail / perch);
    if (chunk > NCH) chunk = NCH;
    if (chunk < 1) chunk = 1;

    setup<<<dim3(1024), dim3(256), 0, stream>>>(w2f, sacc);

    for (int c0 = 0; c0 < NCH; c0 += chunk) {
        int cc = (NCH - c0 < chunk) ? (NCH - c0) : chunk;
        int ngrp = (cc + 5) / 6;
        stage1<<<dim3(512), dim3(512), 0, stream>>>(target, recon, w2f, x1t, c0, cc);
        stage2<<<dim3(64 * ngrp), dim3(256), 0, stream>>>(x1t, w2f, sacc, c0, cc);
    }
    finalize<<<dim3(1), dim3(64), 0, stream>>>(sacc, out);
}

// Round 12
// 61.248 us; speedup vs baseline: 2.2541x; 1.0939x over previous
//
#include <hip/hip_runtime.h>
#include <math.h>

// AWLoss closed-form: f = 24 - (0.5/511^2) * sum_c S1_c^2 / S2_c
// S1 = sum wgt*Re(F), S2 = sum wgt*|F|^2 over half-spectrum k1 in [0,511),
// k2 in [0,256), wgt = 1 for k2==0 else 2, F = conj(X)Y / |X|^2
// (1e-9 pre-whitening is < 1e-12 relative to |X|^2 ~ 1e4 -> dropped).
// X = DFT2(pad(target)), Y = DFT2(pad(recon)), pad offset 127.
//
// Round-12: stage1 rebuilt in stage2's proven shape -- twiddle-stationary in
// VGPRs (wave owns a t-pair, no asm pins), 64 input rows staged once to LDS
// as bf16 fragments (one barrier), kk-outer loop at 1 ds_read : 4 MFMA, zero
// task redundancy (was 4x). stage2 unchanged from R11.

#define NCH 48
#define PADOFF 127
#define TWO_PI_F 6.283185307179586f

typedef float f32x4 __attribute__((ext_vector_type(4)));
typedef short s16x8 __attribute__((ext_vector_type(8)));
typedef unsigned short u16;

typedef __attribute__((address_space(1))) const unsigned char* gas_p;
typedef __attribute__((address_space(3))) unsigned char* las_p;

union frag_u { u16 u[8]; s16x8 v; };

__device__ __forceinline__ u16 f2bf(float f) {
    union { float f; unsigned u; } x; x.f = f;
    unsigned r = x.u + 0x7FFFu + ((x.u >> 16) & 1u);
    return (u16)(r >> 16);
}

#define MFMA16(A, B, C) __builtin_amdgcn_mfma_f32_16x16x32_bf16(A, B, C, 0, 0, 0)

// ---------------- setup: twiddle fragment table + acc zero ----------------
// w2f : fragments [kt(32)][c(2)][kk(8)][lane(64)][j(8)] bf16
//       element: tw((16kt + (l&15)) * (32kk + 8(l>>4) + j + 127) mod 511),
//       c=0 cos, c=1 sin; rows k1>=511 zeroed.
__global__ __launch_bounds__(256) void setup(u16* __restrict__ w2f,
                                             float* __restrict__ sacc) {
    __shared__ float cs[511], sn[511];
    int tid = threadIdx.x;
    for (int i = tid; i < 511; i += 256) {
        float a = -TWO_PI_F * (float)i / 511.0f;
        cs[i] = cosf(a);
        sn[i] = sinf(a);
    }
    __syncthreads();

    int i = blockIdx.x * 256 + tid;      // i < 262144
    int j = i & 7, l = (i >> 3) & 63, kk = (i >> 9) & 7;
    int c = (i >> 12) & 1, kt = i >> 13;
    int k1 = 16 * kt + (l & 15);
    u16 v = 0;
    if (k1 < 511) {
        int n = 32 * kk + 8 * (l >> 4) + j;
        int p = (k1 * (n + PADOFF)) % 511;
        v = f2bf(c ? sn[p] : cs[p]);
    }
    w2f[i] = v;
    if (blockIdx.x == 0 && tid < 2 * NCH) sacc[tid] = 0.0f;
}

// ---------------- stage 1: DFT along W (twiddle-stationary) ----------------
// X1[n1][k2] = sum_b src[n1][b] * W[b][k2]; x1t[lc*4+tsel*2+c][k2][n1] bf16.
// grid = 16cc blocks x 256 thr: h = bid&1 (t-half), q = (bid>>1)&3 (row
// quarter), img = bid>>3. Wave w owns t-pair {8h+2w, 8h+2w+1} twiddles in
// VGPRs; 64 input rows staged once to LDS as bf16 A-fragments.
__global__ __launch_bounds__(256, 2) void stage1(const float* __restrict__ target,
                                                 const float* __restrict__ recon,
                                                 const u16* __restrict__ w2f,
                                                 u16* __restrict__ x1t,
                                                 int c0) {
    int tid = threadIdx.x;
    int w = tid >> 6, l = tid & 63;
    int lm = l & 15, lh = l >> 4;
    int h   = blockIdx.x & 1;
    int q   = (blockIdx.x >> 1) & 3;
    int imgl = blockIdx.x >> 3;          // [0, 2cc)
    int lc = imgl >> 1;
    int tsel = imgl & 1;
    const float* src = (tsel == 0 ? target : recon) + (size_t)(c0 + lc) * 65536;
    int r0 = 64 * q;

    __shared__ u16 lin[16384];           // 32 KiB: [(s*8+kk)*512 + l*8]

    // ---- stage 64 rows f32 -> bf16 fragments (thread = (row, 64-col chunk))
    {
        int row = tid >> 2;              // 0..63
        int cg  = tid & 3;
        const float* rp = src + (size_t)(r0 + row) * 256 + cg * 64;
        float4 v[16];
        #pragma unroll
        for (int i = 0; i < 16; ++i) v[i] = *(const float4*)(rp + 4 * i);
        u16 b[64];
        #pragma unroll
        for (int i = 0; i < 16; ++i) {
            b[4*i]   = f2bf(v[i].x); b[4*i+1] = f2bf(v[i].y);
            b[4*i+2] = f2bf(v[i].z); b[4*i+3] = f2bf(v[i].w);
        }
        int s = row >> 4, lmw = row & 15;
        #pragma unroll
        for (int i2 = 0; i2 < 8; ++i2) {
            int col0 = cg * 64 + i2 * 8;
            int kk = col0 >> 5, lhw = (col0 >> 3) & 3;
            u16* dst = &lin[((s * 8 + kk) * 512) + (lhw * 16 + lmw) * 8];
            *(s16x8*)dst = *(const s16x8*)&b[i2 * 8];
        }
    }

    // ---- stationary twiddles: t-pair {t0, t0+1}, planes cos/sin
    int t0 = 8 * h + 2 * w;
    s16x8 tw00[8], tw01[8], tw10[8], tw11[8];   // [t][c][kk]
    {
        const u16* p0 = w2f + (size_t)t0 * 8192 + l * 8;
        const u16* p1 = w2f + (size_t)(t0 + 1) * 8192 + l * 8;
        #pragma unroll
        for (int kk = 0; kk < 8; ++kk) {
            tw00[kk] = *(const s16x8*)(p0 + kk * 512);
            tw01[kk] = *(const s16x8*)(p0 + 4096 + kk * 512);
            tw10[kk] = *(const s16x8*)(p1 + kk * 512);
            tw11[kk] = *(const s16x8*)(p1 + 4096 + kk * 512);
        }
    }
    __syncthreads();

    // ---- kk-outer: 4 ds_read feed 16 MFMA (4 subtiles x 4 (t,c))
    f32x4 a00[4], a01[4], a10[4], a11[4];
    #pragma unroll
    for (int s = 0; s < 4; ++s) {
        a00[s] = (f32x4){0,0,0,0}; a01[s] = (f32x4){0,0,0,0};
        a10[s] = (f32x4){0,0,0,0}; a11[s] = (f32x4){0,0,0,0};
    }
    #pragma unroll
    for (int kk = 0; kk < 8; ++kk) {
        s16x8 af[4];
        #pragma unroll
        for (int s = 0; s < 4; ++s)
            af[s] = *(const s16x8*)&lin[((s * 8 + kk) * 512) + l * 8];
        #pragma unroll
        for (int s = 0; s < 4; ++s) {
            a00[s] = MFMA16(af[s], tw00[kk], a00[s]);
            a01[s] = MFMA16(af[s], tw01[kk], a01[s]);
            a10[s] = MFMA16(af[s], tw10[kk], a10[s]);
            a11[s] = MFMA16(af[s], tw11[kk], a11[s]);
        }
    }

    // ---- epilogue: D (m = 4lh+r, n = lm): n1 = r0+16s+4lh+r, k2 = 16t+lm
    u16* chdst = x1t + (size_t)(lc * 4 + tsel * 2) * 65536;
    #pragma unroll
    for (int s = 0; s < 4; ++s) {
        size_t off0 = (size_t)(16 * t0 + lm) * 256 + r0 + 16 * s + 4 * lh;
        size_t off1 = off0 + 4096;       // (t0+1): +16*256
        ushort4 o;
        o.x = f2bf(a00[s][0]); o.y = f2bf(a00[s][1]);
        o.z = f2bf(a00[s][2]); o.w = f2bf(a00[s][3]);
        *(ushort4*)(chdst + off0) = o;
        o.x = f2bf(a01[s][0]); o.y = f2bf(a01[s][1]);
        o.z = f2bf(a01[s][2]); o.w = f2bf(a01[s][3]);
        *(ushort4*)(chdst + 65536 + off0) = o;
        o.x = f2bf(a10[s][0]); o.y = f2bf(a10[s][1]);
        o.z = f2bf(a10[s][2]); o.w = f2bf(a10[s][3]);
        *(ushort4*)(chdst + off1) = o;
        o.x = f2bf(a11[s][0]); o.y = f2bf(a11[s][1]);
        o.z = f2bf(a11[s][2]); o.w = f2bf(a11[s][3]);
        *(ushort4*)(chdst + 65536 + off1) = o;
    }
}

// ---------------- stage 2: twiddle-stationary, x1t streamed via LDS ----------------
// (unchanged from round 11)
__global__ __launch_bounds__(256, 2) void stage2(const u16* __restrict__ x1t,
                                                 const u16* __restrict__ w2f,
                                                 float* __restrict__ sacc,
                                                 int c0, int cc) {
    int tid = threadIdx.x;
    int w = tid >> 6, l = tid & 63;
    int lm = l & 15, lh = l >> 4;
    int t   = blockIdx.x & 15;
    int o   = (blockIdx.x >> 4) & 3;
    int chg = blockIdx.x >> 6;
    int ch0 = chg * 6;
    int nch = cc - ch0; if (nch > 6) nch = 6;
    if (nch <= 0) return;

    __shared__ u16 sbufA[16384];
    __shared__ u16 sbufB[16384];
    __shared__ float red[4][12];

    int kt0 = 8 * o + 2 * w;
    s16x8 twr0[8], twi0[8], twr1[8], twi1[8];
    {
        const u16* p0 = w2f + (size_t)kt0 * 8192 + l * 8;
        const u16* p1 = w2f + (size_t)(kt0 + 1) * 8192 + l * 8;
        #pragma unroll
        for (int kk = 0; kk < 8; ++kk) {
            twr0[kk] = *(const s16x8*)(p0 + kk * 512);
            twi0[kk] = *(const s16x8*)(p0 + 4096 + kk * 512);
            twr1[kk] = *(const s16x8*)(p1 + kk * 512);
            twi1[kk] = *(const s16x8*)(p1 + 4096 + kk * 512);
        }
    }

    int k2 = 16 * t + lm;
    float wgt = (k2 == 0) ? 1.f : 2.f;
    int rowoff = (16 * t + lm) * 256 + 8 * lh;
    float s1a[6] = {0,0,0,0,0,0}, s2a[6] = {0,0,0,0,0,0};

#define STAGE(BUF, LC) do {                                                   \
    const u16* cb_ = x1t + (size_t)(4 * (LC)) * 65536;                        \
    _Pragma("unroll")                                                         \
    for (int q = 0; q < 8; ++q) {                                             \
        int pair_ = w * 8 + q;                                                \
        int p_ = pair_ >> 3, kk_ = pair_ & 7;                                 \
        const u16* g_ = cb_ + (size_t)p_ * 65536 + rowoff + 32 * kk_;         \
        __builtin_amdgcn_global_load_lds((gas_p)g_,                           \
            (las_p)&BUF[pair_ * 512], 16, 0, 0);                              \
    } } while (0)

#define COMPUTE(BUF, I) do {                                                  \
    f32x4 c0rr = {0,0,0,0}, c0ii = {0,0,0,0}, c0ri = {0,0,0,0}, c0ir = {0,0,0,0}; \
    f32x4 d0rr = {0,0,0,0}, d0ii = {0,0,0,0}, d0ri = {0,0,0,0}, d0ir = {0,0,0,0}; \
    f32x4 c1rr = {0,0,0,0}, c1ii = {0,0,0,0}, c1ri = {0,0,0,0}, c1ir = {0,0,0,0}; \
    f32x4 d1rr = {0,0,0,0}, d1ii = {0,0,0,0}, d1ri = {0,0,0,0}, d1ir = {0,0,0,0}; \
    _Pragma("unroll")                                                         \
    for (int kk = 0; kk < 8; ++kk) {                                          \
        const u16* fb = &BUF[kk * 512 + l * 8];                               \
        s16x8 ar = *(const s16x8*)(fb);                                       \
        s16x8 ai = *(const s16x8*)(fb + 4096);                                \
        s16x8 br = *(const s16x8*)(fb + 8192);                                \
        s16x8 bi = *(const s16x8*)(fb + 12288);                               \
        c0rr = MFMA16(twr0[kk], ar, c0rr);                                    \
        c0ii = MFMA16(twi0[kk], ai, c0ii);                                    \
        c0ri = MFMA16(twr0[kk], ai, c0ri);                                    \
        c0ir = MFMA16(twi0[kk], ar, c0ir);                                    \
        d0rr = MFMA16(twr0[kk], br, d0rr);                                    \
        d0ii = MFMA16(twi0[kk], bi, d0ii);                                    \
        d0ri = MFMA16(twr0[kk], bi, d0ri);                                    \
        d0ir = MFMA16(twi0[kk], br, d0ir);                                    \
        c1rr = MFMA16(twr1[kk], ar, c1rr);                                    \
        c1ii = MFMA16(twi1[kk], ai, c1ii);                                    \
        c1ri = MFMA16(twr1[kk], ai, c1ri);                                    \
        c1ir = MFMA16(twi1[kk], ar, c1ir);                                    \
        d1rr = MFMA16(twr1[kk], br, d1rr);                                    \
        d1ii = MFMA16(twi1[kk], bi, d1ii);                                    \
        d1ri = MFMA16(twr1[kk], bi, d1ri);                                    \
        d1ir = MFMA16(twi1[kk], br, d1ir);                                    \
    }                                                                         \
    _Pragma("unroll")                                                         \
    for (int r = 0; r < 4; ++r) {                                             \
        {                                                                     \
            float Xr = c0rr[r] - c0ii[r], Xi = c0ri[r] + c0ir[r];             \
            float Yr = d0rr[r] - d0ii[r], Yi = d0ri[r] + d0ir[r];             \
            float Pr = Xr * Yr + Xi * Yi;                                     \
            float Pi = Xr * Yi - Xi * Yr;                                     \
            float Q  = Xr * Xr + Xi * Xi;                                     \
            float inv = 1.0f / (Q * Q + 1e-30f);                              \
            s1a[I] += wgt * Pr * Q * inv;                                     \
            s2a[I] += wgt * (Pr * Pr + Pi * Pi) * inv;                        \
        }                                                                     \
        {                                                                     \
            int k1 = 16 * (kt0 + 1) + 4 * lh + r;                             \
            float wg2 = (k1 < 511) ? wgt : 0.f;                               \
            float Xr = c1rr[r] - c1ii[r], Xi = c1ri[r] + c1ir[r];             \
            float Yr = d1rr[r] - d1ii[r], Yi = d1ri[r] + d1ir[r];             \
            float Pr = Xr * Yr + Xi * Yi;                                     \
            float Pi = Xr * Yi - Xi * Yr;                                     \
            float Q  = Xr * Xr + Xi * Xi;                                     \
            float inv = 1.0f / (Q * Q + 1e-30f);                              \
            s1a[I] += wg2 * Pr * Q * inv;                                     \
            s2a[I] += wg2 * (Pr * Pr + Pi * Pi) * inv;                        \
        }                                                                     \
    } } while (0)

    STAGE(sbufA, ch0);
    __syncthreads();

    #pragma unroll
    for (int i = 0; i < 6; i += 2) {
        if (i >= nch) break;
        if (i + 1 < nch) STAGE(sbufB, ch0 + i + 1);
        COMPUTE(sbufA, i);
        __syncthreads();
        if (i + 1 < nch) {
            if (i + 2 < nch) STAGE(sbufA, ch0 + i + 2);
            COMPUTE(sbufB, i + 1);
            __syncthreads();
        }
    }
#undef STAGE
#undef COMPUTE

    #pragma unroll
    for (int i = 0; i < 6; ++i) {
        #pragma unroll
        for (int off = 32; off > 0; off >>= 1) {
            s1a[i] += __shfl_down(s1a[i], off);
            s2a[i] += __shfl_down(s2a[i], off);
        }
    }
    if (l == 0) {
        #pragma unroll
        for (int i = 0; i < 6; ++i) {
            red[w][2 * i]     = s1a[i];
            red[w][2 * i + 1] = s2a[i];
        }
    }
    __syncthreads();
    if (tid < 12) {
        int i = tid >> 1;
        if (i < nch) {
            float v = red[0][tid] + red[1][tid] + red[2][tid] + red[3][tid];
            atomicAdd(&sacc[(tid & 1) * NCH + c0 + ch0 + i], v);
        }
    }
}

__global__ void finalize(const float* __restrict__ s, float* __restrict__ out) {
    int t = threadIdx.x;
    float v = 0.f;
    if (t < NCH) {
        float s1 = s[t], s2 = s[NCH + t];
        v = (s2 != 0.f) ? (s1 * s1) / s2 : 0.f;
    }
    for (int off = 32; off > 0; off >>= 1) v += __shfl_down(v, off);
    if (t == 0) out[0] = 24.0f - 0.5f * v / 261121.0f;
}

// ---------------- launch ----------------
extern "C" void kernel_launch(void* const* d_in, const int* in_sizes, int n_in,
                              void* d_out, int out_size, void* d_ws, size_t ws_size,
                              hipStream_t stream) {
    const float* recon  = (const float*)d_in[0];
    const float* target = (const float*)d_in[1];
    float* out = (float*)d_out;
    char* ws = (char*)d_ws;

    const size_t OFF_W2F = 0;                        // 524288 B
    const size_t OFF_S   = OFF_W2F + 524288;         // 512 B
    const size_t OFF_X1  = OFF_S + 512;

    u16*   w2f  = (u16*)(ws + OFF_W2F);
    float* sacc = (float*)(ws + OFF_S);
    u16*   x1t  = (u16*)(ws + OFF_X1);

    const size_t perch = 4ull * 65536 * 2;           // 512 KiB per channel
    size_t avail = (ws_size > OFF_X1) ? ws_size - OFF_X1 : 0;
    int chunk = (int)(avail / perch);
    if (chunk > NCH) chunk = NCH;
    if (chunk < 1) chunk = 1;

    setup<<<dim3(1024), dim3(256), 0, stream>>>(w2f, sacc);

    for (int c0 = 0; c0 < NCH; c0 += chunk) {
        int cc = (NCH - c0 < chunk) ? (NCH - c0) : chunk;
        int ngrp = (cc + 5) / 6;
        stage1<<<dim3(16 * cc), dim3(256), 0, stream>>>(target, recon, w2f, x1t, c0);
        stage2<<<dim3(64 * ngrp), dim3(256), 0, stream>>>(x1t, w2f, sacc, c0, cc);
    }
    finalize<<<dim3(1), dim3(64), 0, stream>>>(sacc, out);
}